// Round 4
// baseline (551.854 us; speedup 1.0000x reference)
//
#include <hip/hip_runtime.h>
#include <hip/hip_bf16.h>
#include <math.h>

// Problem constants (from reference)
#define NEXP 8
#define DIM_D 1024
#define DIM_H 4096
#define NB 4096

typedef __attribute__((ext_vector_type(8))) short short8;
typedef __attribute__((ext_vector_type(4))) float floatx4;

__device__ __forceinline__ unsigned short f2bf(float x) {
  __hip_bfloat16 h = __float2bfloat16(x);   // RNE
  unsigned short u;
  __builtin_memcpy(&u, &h, 2);
  return u;
}
__device__ __forceinline__ unsigned int pack2bf(float a, float b) {
  return (unsigned int)f2bf(a) | ((unsigned int)f2bf(b) << 16);
}

// async global->LDS, 16B per lane; LDS dest = wave-uniform base + lane*16
__device__ __forceinline__ void async_copy16(const void* g, void* l) {
  __builtin_amdgcn_global_load_lds(
      (const __attribute__((address_space(1))) unsigned int*)g,
      (__attribute__((address_space(3))) unsigned int*)l, 16, 0, 0);
}

// ---------------- setup: bucket rows by expert (f32 t, bit-exact vs ref) ----
__global__ void setup_kernel(const float* __restrict__ t,
                             int* __restrict__ offs, int* __restrict__ perm) {
  __shared__ int cnt[NEXP];
  __shared__ int cur[NEXP];
  const int tid = threadIdx.x;
  if (tid < NEXP) cnt[tid] = 0;
  __syncthreads();
  for (int i = tid; i < NB; i += 256) {
    int e = (int)(t[i] * 8.0f);             // t/H_STEP, pow2 -> exact
    e = e < 0 ? 0 : (e > NEXP - 1 ? NEXP - 1 : e);
    atomicAdd(&cnt[e], 1);
  }
  __syncthreads();
  if (tid == 0) {
    int s = 0;
    for (int e = 0; e < NEXP; ++e) { offs[e] = s; cur[e] = s; s += cnt[e]; }
    offs[NEXP] = s;
  }
  __syncthreads();
  for (int i = tid; i < NB; i += 256) {
    int e = (int)(t[i] * 8.0f);
    e = e < 0 ? 0 : (e > NEXP - 1 ? NEXP - 1 : e);
    int slot = atomicAdd(&cur[e], 1);
    perm[slot] = i;
  }
}

// ---------------- f32 -> bf16 bulk convert (for y) ----------------
__global__ __launch_bounds__(256)
void cvt_kernel(const float* __restrict__ in, __hip_bfloat16* __restrict__ out) {
  const long long i = ((long long)blockIdx.x * 256 + threadIdx.x) * 8;
  const float4 a = *(const float4*)(in + i);
  const float4 b = *(const float4*)(in + i + 4);
  unsigned int r[4];
  r[0] = pack2bf(a.x, a.y);
  r[1] = pack2bf(a.z, a.w);
  r[2] = pack2bf(b.x, b.y);
  r[3] = pack2bf(b.z, b.w);
  *(uint4*)(out + i) = *(const uint4*)r;
}

// ------- f32 transpose + bf16 convert: in [R][C] f32 -> out [C][R] bf16 ----
// 64x64 tile; LDS u32 [64][36] of packed bf16 pairs (pad 36 breaks pow2 bank
// stride). Load side 16B-vectorized f32, store side 16B-vectorized bf16.
__global__ __launch_bounds__(256)
void transpose_cvt_kernel(const float* __restrict__ in,
                          __hip_bfloat16* __restrict__ out, int R, int C) {
  __shared__ __align__(16) unsigned int tile[64 * 36];
  const long long base = (long long)blockIdx.z * R * C;
  const int c0 = blockIdx.x * 64;
  const int r0 = blockIdx.y * 64;
  const int t = threadIdx.x;
  {
    const int ir = t >> 2, q = t & 3;            // row ir, col chunk q*16
    const float* src = in + base + (long long)(r0 + ir) * C + c0 + q * 16;
    const float4 v0 = *(const float4*)(src);
    const float4 v1 = *(const float4*)(src + 4);
    const float4 v2 = *(const float4*)(src + 8);
    const float4 v3 = *(const float4*)(src + 12);
    unsigned int* dp = &tile[ir * 36 + q * 8];
    dp[0] = pack2bf(v0.x, v0.y);
    dp[1] = pack2bf(v0.z, v0.w);
    dp[2] = pack2bf(v1.x, v1.y);
    dp[3] = pack2bf(v1.z, v1.w);
    dp[4] = pack2bf(v2.x, v2.y);
    dp[5] = pack2bf(v2.z, v2.w);
    dp[6] = pack2bf(v3.x, v3.y);
    dp[7] = pack2bf(v3.z, v3.w);
  }
  __syncthreads();
  {
    const int oc = t >> 2, rq = t & 3;           // out row c0+oc, cols r0+rq*16..
    __align__(16) unsigned int res[8];
#pragma unroll
    for (int m2 = 0; m2 < 8; ++m2) {
      const int d = rq * 16 + m2 * 2;
      const unsigned int a = tile[d * 36 + (oc >> 1)];
      const unsigned int b = tile[(d + 1) * 36 + (oc >> 1)];
      res[m2] = (oc & 1) ? ((a >> 16) | (b & 0xffff0000u))
                         : ((a & 0xffffu) | (b << 16));
    }
    __hip_bfloat16* dstp = out + base + (long long)(c0 + oc) * R + r0 + rq * 16;
    *(uint4*)dstp = *(const uint4*)&res[0];
    *(uint4*)(dstp + 8) = *(const uint4*)&res[4];
  }
}

// ---------------- grouped NT GEMM, m97 structure ----------------
// C[m][n] = sum_k A[m][k] * BT[n][k]; 128x128 tile, BK=32,
// global_load_lds(16B) staging, 4 waves each 64x64 (4x4 of 16x16x32 MFMA).
// MODE 0: A = y_bf16 (rows via perm), epilogue tanh(x+b1) -> hid bf16 (permuted)
// MODE 1: A = hid (contiguous rows), epilogue full output -> f32 out[perm[i]]
template <int MODE>
__global__ __launch_bounds__(256)
void gemm_kernel(const __hip_bfloat16* __restrict__ A,
                 const __hip_bfloat16* __restrict__ BT,   // [E][N][K] bf16
                 const float* __restrict__ bias,          // [E][N] f32
                 const int* __restrict__ offs, const int* __restrict__ perm,
                 void* __restrict__ dstv,                 // MODE0: bf16*, MODE1: f32*
                 const float* __restrict__ yin,           // [B][N] f32 (MODE 1)
                 const float* __restrict__ scales,        // [N] f32 (MODE 1)
                 const float* __restrict__ shifta,
                 const float* __restrict__ shiftb,
                 int K, int N) {
  const int e  = blockIdx.y >> 5;
  const int mt = blockIdx.y & 31;
  const int off = offs[e];
  const int cnt = offs[e + 1] - off;
  const int m0 = mt * 128;
  if (m0 >= cnt) return;                    // early-exit for padded grid
  const int rows = min(128, cnt - m0);
  const int n0 = blockIdx.x * 128;

  __shared__ __align__(16) __hip_bfloat16 As[128 * 32];
  __shared__ __align__(16) __hip_bfloat16 Bs[128 * 32];
  __shared__ int rowmap[128];

  const int tid = threadIdx.x;
  if (tid < 128) {
    int r = tid < rows ? tid : rows - 1;    // clamp: stage valid memory
    rowmap[tid] = (MODE == 0) ? perm[off + m0 + r] : (off + m0 + r);
  }
  __syncthreads();

  const int w = tid >> 6, l = tid & 63;
  // staging: chunk c = w*2+r covers tile rows [c*16, c*16+16), lane l -> 16B
  const __hip_bfloat16* aptr[2];
  const __hip_bfloat16* bptr[2];
  {
    const long long bb = (long long)e * N * K + (long long)n0 * K;
#pragma unroll
    for (int r = 0; r < 2; ++r) {
      const int c = w * 2 + r;
      const int row = c * 16 + (l >> 2);
      const int col = (l & 3) * 8;
      aptr[r] = A + (long long)rowmap[row] * K + col;
      bptr[r] = BT + bb + (long long)row * K + col;
    }
  }

  floatx4 acc[4][4];
#pragma unroll
  for (int i = 0; i < 4; ++i)
#pragma unroll
    for (int j = 0; j < 4; ++j) acc[i][j] = (floatx4){0.f, 0.f, 0.f, 0.f};

  const int wm = w >> 1, wn = w & 1;
  const int fr = l & 15;                    // M (A) / N (B) index in fragment
  const int fk = (l >> 4) * 8;              // K offset in fragment
  const __hip_bfloat16* Afrag = &As[(wm * 64 + fr) * 32 + fk];
  const __hip_bfloat16* Bfrag = &Bs[(wn * 64 + fr) * 32 + fk];

  for (int kt = 0; kt < K; kt += 32) {
#pragma unroll
    for (int r = 0; r < 2; ++r) {
      const int c = w * 2 + r;
      async_copy16(aptr[r], &As[c * 512]);
      async_copy16(bptr[r], &Bs[c * 512]);
      aptr[r] += 32;
      bptr[r] += 32;
    }
    __syncthreads();                         // drains vmcnt before barrier
    short8 af[4], bf[4];
#pragma unroll
    for (int mi = 0; mi < 4; ++mi) af[mi] = *(const short8*)(Afrag + mi * 16 * 32);
#pragma unroll
    for (int ni = 0; ni < 4; ++ni) bf[ni] = *(const short8*)(Bfrag + ni * 16 * 32);
#pragma unroll
    for (int mi = 0; mi < 4; ++mi)
#pragma unroll
      for (int ni = 0; ni < 4; ++ni)
        acc[mi][ni] = __builtin_amdgcn_mfma_f32_16x16x32_bf16(af[mi], bf[ni],
                                                              acc[mi][ni], 0, 0, 0);
    __syncthreads();
  }

  float av = 0.f, bv = 0.f;
  if (MODE == 1) {
    const float sa = 1.f / (1.f + expf(-shifta[0]));
    const float sb = 1.f / (1.f + expf(-shiftb[0]));
    av = 0.0f + sa * (-1.0f - 0.0f);         // EIGINIT + sig*(EIGMIN-EIGINIT)
    bv = 0.0f + sb * (1.0f - 0.0f);          // EIGINIT + sig*(EIGMAX-EIGINIT)
  }

  // C/D layout: col = lane&15, row = (lane>>4)*4 + reg
#pragma unroll
  for (int mi = 0; mi < 4; ++mi) {
#pragma unroll
    for (int r = 0; r < 4; ++r) {
      const int rl = wm * 64 + mi * 16 + (l >> 4) * 4 + r;
      if (rl >= rows) continue;
      const int i = off + m0 + rl;
      const int orig = (MODE == 1) ? perm[i] : 0;
#pragma unroll
      for (int ni = 0; ni < 4; ++ni) {
        const int cg = n0 + wn * 64 + ni * 16 + fr;
        const float x = acc[mi][ni][r] + bias[e * N + cg];
        if (MODE == 0) {
          ((__hip_bfloat16*)dstv)[(long long)i * N + cg] = __float2bfloat16(tanhf(x));
        } else {
          const float sc = 1.f / (1.f + expf(-scales[cg]));
          const float yv = yin[(long long)orig * N + cg];
          const float res = 0.5f * ((bv - av) * sc * x + (av + bv) * yv);
          ((float*)dstv)[(long long)orig * N + cg] = res;   // f32 output!
        }
      }
    }
  }
}

extern "C" void kernel_launch(void* const* d_in, const int* in_sizes, int n_in,
                              void* d_out, int out_size, void* d_ws, size_t ws_size,
                              hipStream_t stream) {
  const float* t      = (const float*)d_in[0];
  const float* y      = (const float*)d_in[1];
  const float* W1     = (const float*)d_in[2];
  const float* b1     = (const float*)d_in[3];
  const float* W2     = (const float*)d_in[4];
  const float* b2     = (const float*)d_in[5];
  const float* scales = (const float*)d_in[6];
  const float* shifta = (const float*)d_in[7];
  const float* shiftb = (const float*)d_in[8];

  // ws layout: [0,64MB)   transposed bf16 weights (W1T, then reused for W2T)
  //            [64,96MB)  hid bf16 [NB][DIM_H], permuted row order
  //            [96,104MB) y_bf16 [NB][DIM_D]
  //            [104MB,..) offs[16] + perm[NB]
  char* ws = (char*)d_ws;
  __hip_bfloat16* WT  = (__hip_bfloat16*)ws;
  __hip_bfloat16* hid = (__hip_bfloat16*)(ws + (size_t)64 * 1024 * 1024);
  __hip_bfloat16* ybf = (__hip_bfloat16*)(ws + (size_t)96 * 1024 * 1024);
  int* offs = (int*)(ws + (size_t)104 * 1024 * 1024);
  int* perm = offs + 16;

  setup_kernel<<<1, 256, 0, stream>>>(t, offs, perm);

  cvt_kernel<<<(NB * DIM_D) / (256 * 8), 256, 0, stream>>>(y, ybf);

  // W1 [E][D][DH] f32 -> WT [E][DH][D] bf16
  transpose_cvt_kernel<<<dim3(DIM_H / 64, DIM_D / 64, NEXP), 256, 0, stream>>>(
      W1, WT, DIM_D, DIM_H);
  // hid = tanh(y @ W1 + b1), grouped by expert
  gemm_kernel<0><<<dim3(DIM_H / 128, NEXP * 32), 256, 0, stream>>>(
      ybf, WT, b1, offs, perm, hid, nullptr, nullptr, nullptr, nullptr,
      DIM_D, DIM_H);
  // W2 [E][DH][D] f32 -> WT [E][D][DH] bf16 (safe reuse: stream-ordered)
  transpose_cvt_kernel<<<dim3(DIM_D / 64, DIM_H / 64, NEXP), 256, 0, stream>>>(
      W2, WT, DIM_H, DIM_D);
  // out = 0.5*((b-a)*sig(scales)*(hid@W2+b2) + (a+b)*y), scattered via perm
  gemm_kernel<1><<<dim3(DIM_D / 128, NEXP * 32), 256, 0, stream>>>(
      hid, WT, b2, offs, perm, d_out, y, scales, shifta, shiftb,
      DIM_H, DIM_D);
}